// Round 2
// baseline (68.238 us; speedup 1.0000x reference)
//
#include <hip/hip_runtime.h>

#define N_IN 512
#define N_VP 12
#define BATCH 65536

#define ROWS 64                   // rows per block == threads per block (1 wave)
#define CHUNK 64                  // floats per row per chunk
#define NCH (N_IN / CHUNK)        // 8 chunks
#define F4PC (CHUNK / 4)          // 16 float4 per row-chunk
#define LDSW (CHUNK + 4)          // padded LDS row stride (floats); 68*4=272B, 16B-aligned

// ---------------------------------------------------------------------------
// Kernel A (1 block, 512 threads): W = phi * Ginv  [512][12]
//   Ginv via Newton iteration Y <- Y(2I - G Y), Y0 = dil*I.
//   (G ~ (1/dil) I: Riemann sum of orthonormal Hermite fns; Newton converges
//    quadratically, 3 iters = fp64-exact for the test regime.)
// ---------------------------------------------------------------------------
__global__ __launch_bounds__(512) void build_W_kernel(const float* __restrict__ w,
                                                      float* __restrict__ Wg) {
    __shared__ double sphi[N_IN][N_VP];      // 48 KB
    __shared__ double Gp[2][N_VP][N_VP];
    __shared__ double G[N_VP][N_VP], Y[N_VP][N_VP], T[N_VP][N_VP];

    const int tid = threadIdx.x;
    const double dil = (double)w[0];
    const double tr  = (double)w[1];

    // phi row n = tid (kept in regs for the final W product)
    double ph[N_VP];
    {
        const double tt = (double)tid - 0.5 * (double)(N_IN - 1);
        const double xv = dil * (tt - tr);
        double pm2 = 0.7511255444649425021236 * exp(-0.5 * xv * xv);  // pi^-1/4
        double pm1 = 1.4142135623730950488017 * xv * pm2;             // sqrt(2)
        ph[0] = pm2; ph[1] = pm1;
#pragma unroll
        for (int k = 2; k < N_VP; ++k) {
            const double pk = sqrt(2.0 / (double)k) * xv * pm1
                            - sqrt((double)(k - 1) / (double)k) * pm2;
            ph[k] = pk; pm2 = pm1; pm1 = pk;
        }
#pragma unroll
        for (int k = 0; k < N_VP; ++k) sphi[tid][k] = ph[k];
    }
    __syncthreads();

    // G = phi^T phi : 2 threads per (i,j) pair, 256 samples each
    if (tid < 288) {
        const int p = tid >> 1;
        const int i = p / N_VP, j = p % N_VP;
        const int m0 = (tid & 1) * 256;
        double s0 = 0.0, s1 = 0.0;
        for (int m = m0; m < m0 + 256; m += 2) {
            s0 += sphi[m][i] * sphi[m][j];
            s1 += sphi[m + 1][i] * sphi[m + 1][j];
        }
        Gp[tid & 1][i][j] = s0 + s1;
    }
    __syncthreads();
    const int ii = (tid < 144) ? tid / N_VP : 0;
    const int jj = (tid < 144) ? tid % N_VP : 0;
    if (tid < 144) {
        G[ii][jj] = Gp[0][ii][jj] + Gp[1][ii][jj];
        Y[ii][jj] = (ii == jj) ? dil : 0.0;
    }
    __syncthreads();

    for (int it = 0; it < 3; ++it) {
        if (tid < 144) {
            double s = 0.0;
#pragma unroll
            for (int k = 0; k < N_VP; ++k) s += G[ii][k] * Y[k][jj];
            T[ii][jj] = s;
        }
        __syncthreads();
        double v = 0.0;
        if (tid < 144) {
            double s = 0.0;
#pragma unroll
            for (int k = 0; k < N_VP; ++k) s += Y[ii][k] * T[k][jj];
            v = 2.0 * Y[ii][jj] - s;
        }
        __syncthreads();
        if (tid < 144) Y[ii][jj] = v;
        __syncthreads();
    }

    // W[n][k] = sum_j Y[k][j] * phi[n][j]   (Y symmetric)
#pragma unroll
    for (int k = 0; k < N_VP; ++k) {
        double s = 0.0;
#pragma unroll
        for (int j2 = 0; j2 < N_VP; ++j2) s += Y[k][j2] * ph[j2];
        Wg[tid * N_VP + k] = (float)s;
    }
}

// ---------------------------------------------------------------------------
// Kernel B: out[row][k] = sum_n x[row][n] * W[n][k]
//   Single-wave blocks (no __syncthreads needed; DS pipe is in-order per wave).
//   Coalesced global -> regs -> LDS exchange (+4-float pad) -> thread-per-row
//   serial n with W at wave-uniform indices (SGPR loads).
//   2-deep register prefetch + double-buffered LDS hides HBM latency under
//   the 768-FMA chunk compute.
// ---------------------------------------------------------------------------
__device__ __forceinline__ void issue_loads(const float4* __restrict__ x4,
                                            int c, int t, float4 st[16]) {
#pragma unroll
    for (int k = 0; k < 16; ++k) {
        const int f = k * 64 + t;                  // f in [0,1024): tile float4 id
        st[k] = x4[(size_t)(f >> 4) * (N_IN / 4) + (size_t)c * F4PC + (f & 15)];
    }
}

__device__ __forceinline__ void store_lds(float sb[ROWS][LDSW], int t,
                                          const float4 st[16]) {
#pragma unroll
    for (int k = 0; k < 16; ++k) {
        const int f = k * 64 + t;
        *reinterpret_cast<float4*>(&sb[f >> 4][(f & 15) * 4]) = st[k];
    }
}

__device__ __forceinline__ void compute_chunk(const float sb[ROWS][LDSW], int t, int c,
                                              const float* __restrict__ Wg,
                                              float acc[N_VP]) {
#pragma unroll
    for (int q = 0; q < F4PC; ++q) {
        const float4 xv = *reinterpret_cast<const float4*>(&sb[t][q * 4]);
        const float* __restrict__ wp = Wg + (size_t)(c * F4PC + q) * 48;  // 4 W rows
#pragma unroll
        for (int k = 0; k < N_VP; ++k) acc[k] = fmaf(xv.x, wp[k], acc[k]);
#pragma unroll
        for (int k = 0; k < N_VP; ++k) acc[k] = fmaf(xv.y, wp[12 + k], acc[k]);
#pragma unroll
        for (int k = 0; k < N_VP; ++k) acc[k] = fmaf(xv.z, wp[24 + k], acc[k]);
#pragma unroll
        for (int k = 0; k < N_VP; ++k) acc[k] = fmaf(xv.w, wp[36 + k], acc[k]);
    }
}

__global__ __launch_bounds__(64) void coeffs_kernel(const float* __restrict__ x,
                                                    const float* __restrict__ Wg,
                                                    float* __restrict__ out) {
    __shared__ float sb[2][ROWS][LDSW];            // 2*64*68*4 = 34.8 KB
    const int t = threadIdx.x;
    const size_t rowbase = (size_t)blockIdx.x * ROWS;
    const float4* __restrict__ x4 =
        reinterpret_cast<const float4*>(x) + rowbase * (N_IN / 4);

    float4 st0[16], st1[16];
    issue_loads(x4, 0, t, st0);
    issue_loads(x4, 1, t, st1);
    store_lds(sb[0], t, st0);

    float acc[N_VP];
#pragma unroll
    for (int k = 0; k < N_VP; ++k) acc[k] = 0.0f;

#pragma unroll
    for (int c = 0; c < NCH; ++c) {
        float4* curslot = (c & 1) ? st1 : st0;     // holds chunk c (already in LDS)
        float4* nxtslot = (c & 1) ? st0 : st1;     // holds chunk c+1 (in regs)
        if (c + 2 < NCH) issue_loads(x4, c + 2, t, curslot);
        if (c + 1 < NCH) store_lds(sb[(c + 1) & 1], t, nxtslot);
        compute_chunk(sb[c & 1], t, c, Wg, acc);
    }

    float* __restrict__ orow = out + (rowbase + (size_t)t) * N_VP;
    reinterpret_cast<float4*>(orow)[0] = make_float4(acc[0], acc[1], acc[2],  acc[3]);
    reinterpret_cast<float4*>(orow)[1] = make_float4(acc[4], acc[5], acc[6],  acc[7]);
    reinterpret_cast<float4*>(orow)[2] = make_float4(acc[8], acc[9], acc[10], acc[11]);
}

extern "C" void kernel_launch(void* const* d_in, const int* in_sizes, int n_in,
                              void* d_out, int out_size, void* d_ws, size_t ws_size,
                              hipStream_t stream) {
    const float* x  = (const float*)d_in[0];   // [65536, 512] fp32
    const float* w  = (const float*)d_in[1];   // [2] fp32
    float* out      = (float*)d_out;           // [65536, 12] fp32
    float* Wg       = (float*)d_ws;            // [512, 12] fp32 scratch

    build_W_kernel<<<1, 512, 0, stream>>>(w, Wg);
    coeffs_kernel<<<BATCH / ROWS, ROWS, 0, stream>>>(x, Wg, out);
}

// Round 3
// 57.429 us; speedup vs baseline: 1.1882x; 1.1882x over previous
//
#include <hip/hip_runtime.h>

#define N_IN 512
#define N_VP 12
#define BATCH 65536

#define SPLIT 4                    // K-split factor
#define COLS_PER_S (N_IN / SPLIT)  // 128 cols per (row, s) thread
#define GROUPS 8                   // 8 groups x 16 floats (= one 64B line each)

// ---------------------------------------------------------------------------
// Kernel A (1 block, 512 threads): W = phi * Ginv  [512][12]
//   Ginv via Newton iteration Y <- Y(2I - G Y), Y0 = dil*I.  fp64 throughout.
// ---------------------------------------------------------------------------
__global__ __launch_bounds__(512) void build_W_kernel(const float* __restrict__ w,
                                                      float* __restrict__ Wg) {
    __shared__ double sphi[N_IN][N_VP];      // 48 KB
    __shared__ double Gp[2][N_VP][N_VP];
    __shared__ double G[N_VP][N_VP], Y[N_VP][N_VP], T[N_VP][N_VP];

    const int tid = threadIdx.x;
    const double dil = (double)w[0];
    const double tr  = (double)w[1];

    double ph[N_VP];
    {
        const double tt = (double)tid - 0.5 * (double)(N_IN - 1);
        const double xv = dil * (tt - tr);
        double pm2 = 0.7511255444649425021236 * exp(-0.5 * xv * xv);  // pi^-1/4
        double pm1 = 1.4142135623730950488017 * xv * pm2;             // sqrt(2)
        ph[0] = pm2; ph[1] = pm1;
#pragma unroll
        for (int k = 2; k < N_VP; ++k) {
            const double pk = sqrt(2.0 / (double)k) * xv * pm1
                            - sqrt((double)(k - 1) / (double)k) * pm2;
            ph[k] = pk; pm2 = pm1; pm1 = pk;
        }
#pragma unroll
        for (int k = 0; k < N_VP; ++k) sphi[tid][k] = ph[k];
    }
    __syncthreads();

    if (tid < 288) {                       // G = phi^T phi, 2 threads per (i,j)
        const int p = tid >> 1;
        const int i = p / N_VP, j = p % N_VP;
        const int m0 = (tid & 1) * 256;
        double s0 = 0.0, s1 = 0.0;
        for (int m = m0; m < m0 + 256; m += 2) {
            s0 += sphi[m][i] * sphi[m][j];
            s1 += sphi[m + 1][i] * sphi[m + 1][j];
        }
        Gp[tid & 1][i][j] = s0 + s1;
    }
    __syncthreads();
    const int ii = (tid < 144) ? tid / N_VP : 0;
    const int jj = (tid < 144) ? tid % N_VP : 0;
    if (tid < 144) {
        G[ii][jj] = Gp[0][ii][jj] + Gp[1][ii][jj];
        Y[ii][jj] = (ii == jj) ? dil : 0.0;
    }
    __syncthreads();

    for (int it = 0; it < 3; ++it) {
        if (tid < 144) {
            double s = 0.0;
#pragma unroll
            for (int k = 0; k < N_VP; ++k) s += G[ii][k] * Y[k][jj];
            T[ii][jj] = s;
        }
        __syncthreads();
        double v = 0.0;
        if (tid < 144) {
            double s = 0.0;
#pragma unroll
            for (int k = 0; k < N_VP; ++k) s += Y[ii][k] * T[k][jj];
            v = 2.0 * Y[ii][jj] - s;
        }
        __syncthreads();
        if (tid < 144) Y[ii][jj] = v;
        __syncthreads();
    }

#pragma unroll
    for (int k = 0; k < N_VP; ++k) {       // W[n][k] = sum_j Y[k][j] phi[n][j]
        double s = 0.0;
#pragma unroll
        for (int j2 = 0; j2 < N_VP; ++j2) s += Y[k][j2] * ph[j2];
        Wg[tid * N_VP + k] = (float)s;
    }
}

// ---------------------------------------------------------------------------
// Kernel B pass 1: partial[row][s][k] = sum_{n in quarter s} x[row][n] W[n][k]
//   thread = (row, s): 4096 waves -> 16 waves/CU (50% occ). No LDS.
//   W indices wave-uniform (s forced to SGPR via readfirstlane) -> s_load.
//   Each group = 4 float4 = one 64B line per thread; 2-deep prefetch.
// ---------------------------------------------------------------------------
__global__ __launch_bounds__(256) void partial_kernel(const float* __restrict__ x,
                                                      const float* __restrict__ Wg,
                                                      float* __restrict__ part) {
    const int gid = blockIdx.x * 256 + threadIdx.x;
    const int row = gid & (BATCH - 1);
    const int s   = __builtin_amdgcn_readfirstlane(gid >> 16);   // wave-uniform

    const float4* __restrict__ xr =
        reinterpret_cast<const float4*>(x + (size_t)row * N_IN + (size_t)s * COLS_PER_S);
    const float* __restrict__ wbase = Wg + (size_t)s * COLS_PER_S * N_VP;

    float acc[N_VP];
#pragma unroll
    for (int k = 0; k < N_VP; ++k) acc[k] = 0.0f;

    float4 buf[2][4];
#pragma unroll
    for (int i = 0; i < 4; ++i) buf[0][i] = xr[i];

#pragma unroll
    for (int g = 0; g < GROUPS; ++g) {                // g compile-time (full unroll)
        if (g + 1 < GROUPS) {
#pragma unroll
            for (int i = 0; i < 4; ++i) buf[(g + 1) & 1][i] = xr[(g + 1) * 4 + i];
        }
#pragma unroll
        for (int i = 0; i < 4; ++i) {
            const float4 xv = buf[g & 1][i];
            const float* __restrict__ w4 = wbase + (g * 16 + i * 4) * N_VP;
#pragma unroll
            for (int k = 0; k < N_VP; ++k) acc[k] = fmaf(xv.x, w4[k], acc[k]);
#pragma unroll
            for (int k = 0; k < N_VP; ++k) acc[k] = fmaf(xv.y, w4[N_VP + k], acc[k]);
#pragma unroll
            for (int k = 0; k < N_VP; ++k) acc[k] = fmaf(xv.z, w4[2 * N_VP + k], acc[k]);
#pragma unroll
            for (int k = 0; k < N_VP; ++k) acc[k] = fmaf(xv.w, w4[3 * N_VP + k], acc[k]);
        }
    }

    float* __restrict__ pr = part + (size_t)row * (SPLIT * N_VP) + s * N_VP;
    reinterpret_cast<float4*>(pr)[0] = make_float4(acc[0], acc[1], acc[2],  acc[3]);
    reinterpret_cast<float4*>(pr)[1] = make_float4(acc[4], acc[5], acc[6],  acc[7]);
    reinterpret_cast<float4*>(pr)[2] = make_float4(acc[8], acc[9], acc[10], acc[11]);
}

// ---------------------------------------------------------------------------
// Kernel B pass 2: out[row][k] = sum_s partial[row][s][k]
//   thread-per-row; 12 contiguous independent float4 loads.
// ---------------------------------------------------------------------------
__global__ __launch_bounds__(256) void reduce_kernel(const float* __restrict__ part,
                                                     float* __restrict__ out) {
    const int row = blockIdx.x * 256 + threadIdx.x;
    const float4* __restrict__ p =
        reinterpret_cast<const float4*>(part + (size_t)row * (SPLIT * N_VP));

    float4 a0 = p[0], a1 = p[1],  a2 = p[2];     // s=0
    float4 b0 = p[3], b1 = p[4],  b2 = p[5];     // s=1
    float4 c0 = p[6], c1 = p[7],  c2 = p[8];     // s=2
    float4 d0 = p[9], d1 = p[10], d2 = p[11];    // s=3

    float4 r0, r1, r2;
    r0.x = (a0.x + b0.x) + (c0.x + d0.x);  r0.y = (a0.y + b0.y) + (c0.y + d0.y);
    r0.z = (a0.z + b0.z) + (c0.z + d0.z);  r0.w = (a0.w + b0.w) + (c0.w + d0.w);
    r1.x = (a1.x + b1.x) + (c1.x + d1.x);  r1.y = (a1.y + b1.y) + (c1.y + d1.y);
    r1.z = (a1.z + b1.z) + (c1.z + d1.z);  r1.w = (a1.w + b1.w) + (c1.w + d1.w);
    r2.x = (a2.x + b2.x) + (c2.x + d2.x);  r2.y = (a2.y + b2.y) + (c2.y + d2.y);
    r2.z = (a2.z + b2.z) + (c2.z + d2.z);  r2.w = (a2.w + b2.w) + (c2.w + d2.w);

    float4* __restrict__ orow = reinterpret_cast<float4*>(out + (size_t)row * N_VP);
    orow[0] = r0; orow[1] = r1; orow[2] = r2;
}

extern "C" void kernel_launch(void* const* d_in, const int* in_sizes, int n_in,
                              void* d_out, int out_size, void* d_ws, size_t ws_size,
                              hipStream_t stream) {
    const float* x  = (const float*)d_in[0];   // [65536, 512] fp32
    const float* w  = (const float*)d_in[1];   // [2] fp32
    float* out      = (float*)d_out;           // [65536, 12] fp32
    float* Wg       = (float*)d_ws;            // [512][12] fp32
    float* part     = (float*)d_ws + 8192;     // [65536][4][12] fp32 (12.6 MB)

    build_W_kernel<<<1, 512, 0, stream>>>(w, Wg);
    partial_kernel<<<BATCH * SPLIT / 256, 256, 0, stream>>>(x, Wg, part);
    reduce_kernel<<<BATCH / 256, 256, 0, stream>>>(part, out);
}

// Round 5
// 42.840 us; speedup vs baseline: 1.5929x; 1.3406x over previous
//
#include <hip/hip_runtime.h>

#define N_IN 512
#define N_VP 12
#define BATCH 65536

#define SPLIT 4                   // col quarters; wave s of each block owns one
#define ROWS 64                   // rows per block (= lanes per wave)
#define CPW (N_IN / SPLIT)        // 128 cols per wave
#define CHUNK 16                  // cols staged per chunk
#define NCHW (CPW / CHUNK)        // 8 chunks per wave

// ---------------------------------------------------------------------------
// Kernel A (1 block, 512 threads, fp32): W = phi * Ginv  [512][12]
//   Ginv via Newton Y <- Y(2I - G Y), Y0 = dil*I (G ~ (1/dil) I).
// ---------------------------------------------------------------------------
__global__ __launch_bounds__(512) void build_W_kernel(const float* __restrict__ w,
                                                      float* __restrict__ Wg) {
    __shared__ float sphiT[N_VP][N_IN];        // transposed: rows contiguous (24 KB)
    __shared__ float Gp[2][N_VP][N_VP];
    __shared__ float G[N_VP][N_VP], Y[N_VP][N_VP], T[N_VP][N_VP];

    const int tid = threadIdx.x;
    const float dil = w[0];
    const float tr  = w[1];

    float ph[N_VP];
    {
        const float t  = (float)tid - 0.5f * (float)(N_IN - 1);
        const float xs = dil * (t - tr);
        ph[0] = 0.7511255444649425f * expf(-0.5f * xs * xs);   // pi^-1/4
        ph[1] = 1.4142135623730951f * xs * ph[0];
#pragma unroll
        for (int k = 2; k < N_VP; ++k)
            ph[k] = sqrtf(2.0f / (float)k) * xs * ph[k - 1]
                  - sqrtf((float)(k - 1) / (float)k) * ph[k - 2];
#pragma unroll
        for (int k = 0; k < N_VP; ++k) sphiT[k][tid] = ph[k];
    }
    __syncthreads();

    if (tid < 288) {                 // G = phi^T phi : 2 threads per (i,j)
        const int p = tid >> 1;
        const int i = p / N_VP, j = p % N_VP;
        const int m0 = (tid & 1) * 256;
        const float4* __restrict__ pi = reinterpret_cast<const float4*>(&sphiT[i][m0]);
        const float4* __restrict__ pj = reinterpret_cast<const float4*>(&sphiT[j][m0]);
        float s = 0.0f;
#pragma unroll 4
        for (int q = 0; q < 64; ++q) {
            const float4 a = pi[q], b = pj[q];
            s += a.x * b.x + a.y * b.y + a.z * b.z + a.w * b.w;
        }
        Gp[tid & 1][i][j] = s;
    }
    __syncthreads();
    const int ii = (tid < 144) ? tid / N_VP : 0;
    const int jj = (tid < 144) ? tid % N_VP : 0;
    if (tid < 144) {
        G[ii][jj] = Gp[0][ii][jj] + Gp[1][ii][jj];
        Y[ii][jj] = (ii == jj) ? dil : 0.0f;
    }
    __syncthreads();

    for (int it = 0; it < 3; ++it) {
        if (tid < 144) {
            float s = 0.0f;
#pragma unroll
            for (int k = 0; k < N_VP; ++k) s += G[ii][k] * Y[k][jj];
            T[ii][jj] = s;
        }
        __syncthreads();
        float v = 0.0f;
        if (tid < 144) {
            float s = 0.0f;
#pragma unroll
            for (int k = 0; k < N_VP; ++k) s += Y[ii][k] * T[k][jj];
            v = 2.0f * Y[ii][jj] - s;
        }
        __syncthreads();
        if (tid < 144) Y[ii][jj] = v;
        __syncthreads();
    }

#pragma unroll
    for (int k = 0; k < N_VP; ++k) {          // W[n][k] = sum_j Y[k][j] phi[n][j]
        float s = 0.0f;
#pragma unroll
        for (int j2 = 0; j2 < N_VP; ++j2) s += Y[k][j2] * ph[j2];
        Wg[tid * N_VP + k] = s;
    }
}

// ---------------------------------------------------------------------------
// Kernel B: out = x @ W, fused split-K + reduce.
//   Block = 256 thr = 4 waves; wave s owns cols [s*128,(s+1)*128) of 64 rows.
//   Coalesced global->reg->LDS (XOR q-swizzle; reads hit the 8-access/bank
//   floor), wave-private double buffer => no barriers in the pipeline.
//   W via wave-uniform SGPR loads. Final cross-wave reduce in LDS (2 barriers).
//
//   Buffer roles per iteration c (R2-verified rotation, R4's bug fixed):
//     cur = (c&1)?preB:preA  -- held chunk c, already staged to LDS -> free;
//                               receives the chunk c+2 global load.
//     nxt = (c&1)?preA:preB  -- holds chunk c+1 in regs; gets stored to LDS.
// ---------------------------------------------------------------------------
__device__ __forceinline__ void load_chunk(const float* __restrict__ xq,
                                           const int off[4], int c, float4 pre[4]) {
#pragma unroll
    for (int i = 0; i < 4; ++i)
        pre[i] = *reinterpret_cast<const float4*>(xq + off[i] + c * CHUNK);
}

__device__ __forceinline__ void store_chunk(float4* __restrict__ dst, int lane,
                                            const float4 pre[4]) {
#pragma unroll
    for (int i = 0; i < 4; ++i) dst[i * 64 + lane] = pre[i];
}

__device__ __forceinline__ void compute_chunk(const float4* __restrict__ buf,
                                              int lane, int qx,
                                              const float* __restrict__ wb,
                                              float acc[N_VP]) {
#pragma unroll
    for (int q = 0; q < 4; ++q) {
        const float4 xv = buf[(lane << 2) + (q ^ qx)];   // global col-group q
        const float* __restrict__ w4 = wb + q * (4 * N_VP);
#pragma unroll
        for (int k = 0; k < N_VP; ++k) acc[k] = fmaf(xv.x, w4[k], acc[k]);
#pragma unroll
        for (int k = 0; k < N_VP; ++k) acc[k] = fmaf(xv.y, w4[N_VP + k], acc[k]);
#pragma unroll
        for (int k = 0; k < N_VP; ++k) acc[k] = fmaf(xv.z, w4[2 * N_VP + k], acc[k]);
#pragma unroll
        for (int k = 0; k < N_VP; ++k) acc[k] = fmaf(xv.w, w4[3 * N_VP + k], acc[k]);
    }
}

__global__ __launch_bounds__(256, 4) void coeffs_kernel(const float* __restrict__ x,
                                                        const float* __restrict__ Wg,
                                                        float* __restrict__ out) {
    __shared__ float4 sb[SPLIT][2][256];       // 32 KB; wave-private slices
    const int tid  = threadIdx.x;
    const int lane = tid & 63;
    const int s    = __builtin_amdgcn_readfirstlane(tid >> 6);
    const int qx   = (lane >> 1) & 3;
    const size_t rowbase = (size_t)blockIdx.x * ROWS;
    const float* __restrict__ xq = x + rowbase * N_IN + (size_t)s * CPW;
    const float* __restrict__ wbase = Wg + s * CPW * N_VP;

    // lane-dependent global float4 offsets (floats), constant across chunks.
    // staging instr i, lane: tile float4 f = i*64+lane -> row t=f>>2, slot q0=f&3,
    // global col-group qg = q0 ^ ((t>>1)&3)  (XOR swizzle, stays within 64B line)
    int off[4];
#pragma unroll
    for (int i = 0; i < 4; ++i) {
        const int f = i * 64 + lane, t = f >> 2, q0 = f & 3;
        const int qg = q0 ^ ((t >> 1) & 3);
        off[i] = t * N_IN + qg * 4;
    }

    float4 preA[4], preB[4];
    load_chunk(xq, off, 0, preA);
    load_chunk(xq, off, 1, preB);
    store_chunk(&sb[s][0][0], lane, preA);

    float acc[N_VP];
#pragma unroll
    for (int k = 0; k < N_VP; ++k) acc[k] = 0.0f;

#pragma unroll
    for (int c = 0; c < NCHW; ++c) {
        // nxt (holds chunk c+1) -> LDS; then chunk c+2 -> cur (freed buffer).
        if (c + 1 < NCHW) store_chunk(&sb[s][(c + 1) & 1][0], lane,
                                      (c & 1) ? preA : preB);   // nxt
        if (c + 2 < NCHW) load_chunk(xq, off, c + 2,
                                     (c & 1) ? preB : preA);    // cur
        compute_chunk(&sb[s][c & 1][0], lane, qx, wbase + c * (CHUNK * N_VP), acc);
    }

    // ---- cross-wave reduce over s (aliases staging area; barrier-guarded) ----
    __syncthreads();
    float4* part4 = reinterpret_cast<float4*>(&sb[0][0][0]);   // [4][64][3] float4
    part4[s * 192 + lane * 3 + 0] = make_float4(acc[0], acc[1], acc[2],  acc[3]);
    part4[s * 192 + lane * 3 + 1] = make_float4(acc[4], acc[5], acc[6],  acc[7]);
    part4[s * 192 + lane * 3 + 2] = make_float4(acc[8], acc[9], acc[10], acc[11]);
    __syncthreads();
    if (tid < 192) {
        const float4 v0 = part4[tid], v1 = part4[192 + tid];
        const float4 v2 = part4[384 + tid], v3 = part4[576 + tid];
        float4 r;
        r.x = (v0.x + v1.x) + (v2.x + v3.x);
        r.y = (v0.y + v1.y) + (v2.y + v3.y);
        r.z = (v0.z + v1.z) + (v2.z + v3.z);
        r.w = (v0.w + v1.w) + (v2.w + v3.w);
        reinterpret_cast<float4*>(out + rowbase * N_VP)[tid] = r;
    }
}

extern "C" void kernel_launch(void* const* d_in, const int* in_sizes, int n_in,
                              void* d_out, int out_size, void* d_ws, size_t ws_size,
                              hipStream_t stream) {
    const float* x  = (const float*)d_in[0];   // [65536, 512] fp32
    const float* w  = (const float*)d_in[1];   // [2] fp32
    float* out      = (float*)d_out;           // [65536, 12] fp32
    float* Wg       = (float*)d_ws;            // [512][12] fp32

    build_W_kernel<<<1, 512, 0, stream>>>(w, Wg);
    coeffs_kernel<<<BATCH / ROWS, 256, 0, stream>>>(x, Wg, out);
}